// Round 15
// baseline (392.914 us; speedup 1.0000x reference)
//
#include <hip/hip_runtime.h>
#include <cstdint>
#include <cstddef>

#define NN   20000
#define NPAD 20224   // 316*64
#define EE   640000
#define E2   660000   // EE + NN self loops
#define HHD  4
#define CC   64
#define HC   256
#define NEG  0.2f

// counting-sort CSR build geometry
#define NBUK 313     // ceil(20000/64) buckets of 64 dst nodes
#define NBLK 129     // ceil(E2/EPB) edge blocks
#define EPB  5120    // 256 threads * 20 edges
#define PREP_BLKS 5000       // NN*64/256
#define GEMM_BLKS (NPAD / 64) // 316

typedef short bf16x8 __attribute__((ext_vector_type(8)));
typedef float f32x4 __attribute__((ext_vector_type(4)));

__device__ __forceinline__ float sigmoidf_(float x) { return 1.0f / (1.0f + __expf(-x)); }

__device__ __forceinline__ float wred_sum(float v) {
#pragma unroll
    for (int d = 32; d; d >>= 1) v += __shfl_xor(v, d, 64);
    return v;
}

__device__ __forceinline__ int wred_sum_i(int v) {
#pragma unroll
    for (int d = 32; d; d >>= 1) v += __shfl_xor(v, d, 64);
    return v;
}

__device__ __forceinline__ unsigned short f2bf(float f) {
    unsigned u = __float_as_uint(f);
    u = (u + 0x7fff + ((u >> 16) & 1)) >> 16;   // RNE
    return (unsigned short)u;
}
__device__ __forceinline__ float bfval(unsigned short h) { return __uint_as_float(((unsigned)h) << 16); }
__device__ __forceinline__ float bf_lo(unsigned u) { return __uint_as_float(u << 16); }
__device__ __forceinline__ float bf_hi(unsigned u) { return __uint_as_float(u & 0xffff0000u); }

// ---------------- device bodies (shared by standalone + fused kernels) ----------------

__device__ __forceinline__ void hist_body(int bl, const int* __restrict__ ei,
                                          int* __restrict__ bhist, int* h /*LDS NBUK*/) {
    int t = threadIdx.x;
    for (int i = t; i < NBUK; i += 256) h[i] = 0;
    __syncthreads();
    int e0 = bl * EPB;
#pragma unroll 4
    for (int i = t; i < EPB; i += 256) {
        int e = e0 + i;
        if (e < E2) {
            int d = (e < EE) ? ei[EE + e] : (e - EE);
            atomicAdd(&h[d >> 6], 1);
        }
    }
    __syncthreads();
    for (int i = t; i < NBUK; i += 256) bhist[i * NBLK + bl] = h[i];
}

// scatter WITH self-computed bases: each block derives, from the (bucket, block)
// histogram grid (161KB, L2-resident), exactly the old sbase[i*NBLK+bl] values:
//   cur[i] = sum_{j<i} total_j + sum_{b<bl} bhist[i*NBLK+b]
// Row sums are WAVE-PARALLEL (R14's serial per-thread row walk was a ~50us
// latency stall: VALUBusy 1.8%, occupancy 7%): one wave per bucket row, lanes
// read coalesced, predicated partial + total, 2 int shfl reductions.
// csr output bit-identical to the scan_hist path. Block 0 publishes bucket
// starts + E2 sentinel for build_body.
__device__ __forceinline__ void scatter_body(int bl, const int* __restrict__ ei,
                                             const int* __restrict__ bhist,
                                             unsigned int* __restrict__ ebuf,
                                             int* __restrict__ bstart,
                                             int* ih /*LDS >= 2*NBUK+256+NBUK ints*/) {
    int* tot = ih;                  // [NBUK]
    int* par = ih + NBUK;           // [NBUK]
    int* buf = ih + 2 * NBUK;       // [256]
    int* cur = ih + 2 * NBUK + 256; // [NBUK]
    int t = threadIdx.x;
    int wv = t >> 6, lane = t & 63;
    // wave-parallel per-bucket sums: wave wv owns buckets wv, wv+4, ...
    for (int i = wv; i < NBUK; i += 4) {
        const int* row = bhist + i * NBLK;
        int st = 0, sp = 0;
        for (int b = lane; b < NBLK; b += 64) {
            int v = row[b];
            st += v;
            if (b < bl) sp += v;
        }
        st = wred_sum_i(st);
        sp = wred_sum_i(sp);
        if (lane == 0) { tot[i] = st; par[i] = sp; }
    }
    __syncthreads();
    // exclusive scan over bucket totals: thread t owns buckets 2t, 2t+1
    int b0 = t * 2;
    int v0 = (b0 < NBUK) ? tot[b0] : 0;
    int v1 = (b0 + 1 < NBUK) ? tot[b0 + 1] : 0;
    int s = v0 + v1;
    buf[t] = s;
    __syncthreads();
    for (int d = 1; d < 256; d <<= 1) {
        int tv = (t >= d) ? buf[t - d] : 0;
        __syncthreads();
        buf[t] += tv;
        __syncthreads();
    }
    int excl = buf[t] - s;
    if (b0 < NBUK)     cur[b0]     = excl + par[b0];
    if (b0 + 1 < NBUK) cur[b0 + 1] = excl + v0 + par[b0 + 1];
    if (bl == 0) {   // publish bucket starts for build_body (par==0 here)
        if (b0 < NBUK)     bstart[b0]     = excl;
        if (b0 + 1 < NBUK) bstart[b0 + 1] = excl + v0;
        if (t == 0) bstart[NBUK] = E2;
    }
    __syncthreads();
    int e0 = bl * EPB;
#pragma unroll 4
    for (int i = t; i < EPB; i += 256) {
        int e = e0 + i;
        if (e < E2) {
            int s2, d;
            if (e < EE) { s2 = ei[e]; d = ei[EE + e]; }
            else        { s2 = e - EE; d = s2; }
            int p = atomicAdd(&cur[d >> 6], 1);
            ebuf[p] = ((unsigned int)(d & 63) << 15) | (unsigned int)s2;
        }
    }
}

__device__ __forceinline__ void build_body(int bu, const unsigned int* __restrict__ ebuf,
                                           const int* __restrict__ bstart,
                                           int* __restrict__ off, int* __restrict__ csr,
                                           int* hist /*LDS 192 ints: hist|sc|curl*/) {
    int* sc = hist + 64;
    int* curl = hist + 128;
    int t = threadIdx.x;
    int base = bstart[bu];
    int end  = bstart[bu + 1];
    int ne = end - base;
    if (t < 64) hist[t] = 0;
    __syncthreads();
    for (int i = t; i < ne; i += 256) {
        int dl = (int)(ebuf[base + i] >> 15);
        atomicAdd(&hist[dl], 1);
    }
    __syncthreads();
    if (t < 64) sc[t] = hist[t];
    __syncthreads();
    for (int d = 1; d < 64; d <<= 1) {
        int v = (t < 64 && t >= d) ? sc[t - d] : 0;
        __syncthreads();
        if (t < 64) sc[t] += v;
        __syncthreads();
    }
    int n0 = bu * 64;
    if (t < 64) {
        int ex = base + sc[t] - hist[t];   // exclusive prefix -> global offset
        if (n0 + t < NN) off[n0 + t] = ex;
        curl[t] = ex;
    }
    if (bu == NBUK - 1 && t == 0) off[NN] = E2;
    __syncthreads();
    for (int i = t; i < ne; i += 256) {
        unsigned int v = ebuf[base + i];
        int dl = (int)(v >> 15);
        int p = atomicAdd(&curl[dl], 1);
        csr[p] = (int)(v & 0x7fffu);
    }
}

#define WTOT 212992
__device__ __forceinline__ void prep_body(int idx,
                            const float* __restrict__ x,
                            const float* __restrict__ w_in, const float* __restrict__ lin_w0,
                            const float* __restrict__ lin_w12,
                            const float* __restrict__ nc1, const float* __restrict__ oc1,
                            const float* __restrict__ ec1,
                            const float* __restrict__ nb, const float* __restrict__ ob,
                            const float* __restrict__ eb,
                            unsigned short* __restrict__ whi,
                            float* __restrict__ bcat,
                            unsigned short* __restrict__ xh, unsigned short* __restrict__ xl) {
    if (idx < NN * 64) {
        float4 v = ((const float4*)x)[idx];
        ushort4 hi, lo;
        hi.x = f2bf(v.x); lo.x = f2bf(v.x - bfval(hi.x));
        hi.y = f2bf(v.y); lo.y = f2bf(v.y - bfval(hi.y));
        hi.z = f2bf(v.z); lo.z = f2bf(v.z - bfval(hi.z));
        hi.w = f2bf(v.w); lo.w = f2bf(v.w - bfval(hi.w));
        ((ushort4*)xh)[idx] = hi;
        ((ushort4*)xl)[idx] = lo;
    }
    if (idx < 192) {
        int g = idx >> 6, jj = idx & 63;
        const float* b = (g == 0) ? nb : ((g == 1) ? ob : eb);
        bcat[idx] = b[jj];
    }
    if (idx >= WTOT) return;
    float v;
    if (idx < 16384) {
        int n = idx >> 8, k = idx & 255;
        v = w_in[k * 64 + n];
    } else if (idx < 32768) {
        int r = idx - 16384;
        int n = r >> 6, k = r & 63;
        v = lin_w0[k * 256 + n];
    } else if (idx < 98304) {
        int r = idx - 32768;
        int n = r >> 8, k = r & 255;
        v = lin_w12[k * 256 + n];
    } else if (idx < 163840) {
        int r = idx - 98304;
        int n = r >> 8, k = r & 255;
        v = lin_w12[65536 + k * 256 + n];
    } else {
        int r = idx - 163840;
        int n = r >> 8, k = r & 255;
        int g = n >> 6, jj = n & 63;
        const float* w = (g == 0) ? nc1 : ((g == 1) ? oc1 : ec1);
        v = w[k * 64 + jj];
    }
    whi[idx] = f2bf(v);
}

// ---------------- 2-term split MFMA GEMM body: full-K A prefetch + LDS B ----------------
// NT col-tiles processed SEQUENTIALLY: A fragments loaded once, resident across tiles.
// MODE 0: bias+relu -> hi/lo planes.
// MODE 1: bf16 out (gat gather plane) + fused ATTN scores (ct == head).
// MODE 3: fused output heads (ct: 0=node,1=origin,2=etype).
template <int K, int OUT_CH, int MODE, int NT>
__device__ __forceinline__ void gemm_body(
    unsigned short* Bh,   // LDS: 64*(K+8) shorts
    int mb,
    const unsigned short* __restrict__ Ahp, const unsigned short* __restrict__ Alp,
    const unsigned short* __restrict__ Wh,
    const float* __restrict__ bias,
    unsigned short* __restrict__ Outh,
    const float* __restrict__ a_src, const float* __restrict__ a_dst,
    float* __restrict__ s_src, float* __restrict__ s_dst,
    const float* __restrict__ w2n, const float* __restrict__ w2o,
    const float* __restrict__ w2e,
    const float* __restrict__ b2n, const float* __restrict__ b2o,
    const float* __restrict__ b2e,
    unsigned short* __restrict__ Outl,
    float* __restrict__ outbuf, int nreal) {
    constexpr int LB = K + 8;                 // shorts per padded LDS row
    constexpr int NS = K / 32;                // k-steps
    const int tid = threadIdx.x;
    const int wv = tid >> 6, lane = tid & 63;
    const int quad = lane >> 4, ln = lane & 15;
    const int r0 = mb + wv * 16 + ln;

    // 1) issue ALL A-fragment loads once (kept resident across the NT tiles)
    const unsigned short* aph = Ahp + (size_t)r0 * K + quad * 8;
    const unsigned short* apl = Alp + (size_t)r0 * K + quad * 8;
    bf16x8 ah[NS], al[NS];
#pragma unroll
    for (int s = 0; s < NS; s++) {
        ah[s] = *(const bf16x8*)(aph + s * 32);
        al[s] = *(const bf16x8*)(apl + s * 32);
    }

    for (int ct = 0; ct < NT; ct++) {
        const int cb = ct * 64;
        if (ct > 0) __syncthreads();          // previous B tile fully consumed

        // 2) stage B tile into LDS (rows cb..cb+63, k-contig, padded rows)
        constexpr int NCHK = 64 * (K / 8);
#pragma unroll
        for (int i = 0; i < NCHK / 256; i++) {
            int flat = tid + i * 256;
            int r = flat / (K / 8);
            int c = (flat % (K / 8)) * 8;
            *(uint4*)&Bh[r * LB + c] = *(const uint4*)&Wh[(size_t)(cb + r) * K + c];
        }
        __syncthreads();

        f32x4 acc[4];
#pragma unroll
        for (int j = 0; j < 4; j++) {
            acc[j][0] = 0.f; acc[j][1] = 0.f; acc[j][2] = 0.f; acc[j][3] = 0.f;
        }

        // 3) K-loop: LDS B reads + MFMA only (2-term: ah*bh + al*bh)
#pragma unroll
        for (int s = 0; s < NS; s++) {
#pragma unroll
            for (int cg = 0; cg < 4; cg++) {
                bf16x8 bh = *(const bf16x8*)&Bh[(cg * 16 + ln) * LB + quad * 8 + s * 32];
                acc[cg] = __builtin_amdgcn_mfma_f32_16x16x32_bf16(ah[s], bh, acc[cg], 0, 0, 0);
                acc[cg] = __builtin_amdgcn_mfma_f32_16x16x32_bf16(al[s], bh, acc[cg], 0, 0, 0);
            }
        }

        if (MODE == 1) {
            // per-tile == per-head: score over this head's 64 cols only
            float av[4], dv[4];
#pragma unroll
            for (int cg = 0; cg < 4; cg++) {
                av[cg] = a_src[cb + cg * 16 + ln];
                dv[cg] = a_dst[cb + cg * 16 + ln];
            }
#pragma unroll
            for (int reg = 0; reg < 4; reg++) {
                float ps = 0.f, pd = 0.f;
#pragma unroll
                for (int cg = 0; cg < 4; cg++) {
                    float t = acc[cg][reg];
                    ps += t * av[cg];
                    pd += t * dv[cg];
                }
#pragma unroll
                for (int d = 1; d < 16; d <<= 1) {
                    ps += __shfl_xor(ps, d, 64);
                    pd += __shfl_xor(pd, d, 64);
                }
                if (ln == 0) {
                    int row = mb + wv * 16 + quad * 4 + reg;
                    if (row < nreal) {
                        s_src[row * 4 + ct] = ps;
                        s_dst[row * 4 + ct] = pd;
                    }
                }
            }
        }

        if (MODE == 3) {
            float bv[4];
#pragma unroll
            for (int cg = 0; cg < 4; cg++) bv[cg] = bias[cb + cg * 16 + ln];
            if (ct < 2) {
                const float* w2 = (ct == 0) ? w2n : w2o;
                float b2 = (ct == 0) ? b2n[0] : b2o[0];
                float wv2[4];
#pragma unroll
                for (int cg = 0; cg < 4; cg++) wv2[cg] = w2[cg * 16 + ln];
#pragma unroll
                for (int reg = 0; reg < 4; reg++) {
                    float t = 0.f;
#pragma unroll
                    for (int cg = 0; cg < 4; cg++) {
                        float tv = fmaxf(acc[cg][reg] + bv[cg], 0.f);
                        t += tv * wv2[cg];
                    }
#pragma unroll
                    for (int d = 1; d < 16; d <<= 1) t += __shfl_xor(t, d, 64);
                    int row = mb + wv * 16 + quad * 4 + reg;
                    if (ln == 0 && row < nreal)
                        outbuf[ct * NN + row] = sigmoidf_(t + b2);
                }
            } else {
                float4 w4[4];
#pragma unroll
                for (int cg = 0; cg < 4; cg++) w4[cg] = ((const float4*)w2e)[cg * 16 + ln];
#pragma unroll
                for (int reg = 0; reg < 4; reg++) {
                    float e0 = 0.f, e1 = 0.f, e2 = 0.f, e3 = 0.f;
#pragma unroll
                    for (int cg = 0; cg < 4; cg++) {
                        float tv = fmaxf(acc[cg][reg] + bv[cg], 0.f);
                        e0 += tv * w4[cg].x; e1 += tv * w4[cg].y;
                        e2 += tv * w4[cg].z; e3 += tv * w4[cg].w;
                    }
#pragma unroll
                    for (int d = 1; d < 16; d <<= 1) {
                        e0 += __shfl_xor(e0, d, 64); e1 += __shfl_xor(e1, d, 64);
                        e2 += __shfl_xor(e2, d, 64); e3 += __shfl_xor(e3, d, 64);
                    }
                    int row = mb + wv * 16 + quad * 4 + reg;
                    if (ln == 0 && row < nreal) {
                        float4 ev = make_float4(e0 + b2e[0], e1 + b2e[1], e2 + b2e[2], e3 + b2e[3]);
                        *(float4*)&outbuf[2 * NN + row * 4] = ev;
                    }
                }
            }
            continue;
        }

        // D layout: row = quad*4 + reg, col = ln (within each 16x16 tile)
#pragma unroll
        for (int cg = 0; cg < 4; cg++) {
            int col = cb + cg * 16 + ln;
            int rbase = mb + wv * 16 + quad * 4;
#pragma unroll
            for (int reg = 0; reg < 4; reg++) {
                float v = acc[cg][reg];
                int r = rbase + reg;
                if (MODE == 0) {
                    v += bias[col]; v = fmaxf(v, 0.f);
                    unsigned short hi = f2bf(v);
                    Outh[(size_t)r * OUT_CH + col] = hi;
                    Outl[(size_t)r * OUT_CH + col] = f2bf(v - bfval(hi));
                } else if (MODE == 1) {
                    Outh[(size_t)r * OUT_CH + col] = f2bf(v);
                }
            }
        }
    }
}

// ---------------- fused + standalone kernels ----------------

// K1: prep (blocks [0,PREP_BLKS)) || hist (blocks [PREP_BLKS, PREP_BLKS+NBLK))
__global__ __launch_bounds__(256) void prep_hist(
    const float* __restrict__ x,
    const float* __restrict__ w_in, const float* __restrict__ lin_w0,
    const float* __restrict__ lin_w12,
    const float* __restrict__ nc1, const float* __restrict__ oc1,
    const float* __restrict__ ec1,
    const float* __restrict__ nb, const float* __restrict__ ob,
    const float* __restrict__ eb,
    unsigned short* __restrict__ whi, float* __restrict__ bcat,
    unsigned short* __restrict__ xh, unsigned short* __restrict__ xl,
    const int* __restrict__ ei, int* __restrict__ bhist) {
    __shared__ int h[NBUK];
    if (blockIdx.x < PREP_BLKS) {
        prep_body(blockIdx.x * 256 + threadIdx.x, x, w_in, lin_w0, lin_w12,
                  nc1, oc1, ec1, nb, ob, eb, whi, bcat, xh, xl);
    } else {
        hist_body(blockIdx.x - PREP_BLKS, ei, bhist, h);
    }
}

// K2: scatter w/ self-computed bases (blocks [0,NBLK)) || input-proj GEMM
__global__ __launch_bounds__(256) void scatter_proj(
    const int* __restrict__ ei, const int* __restrict__ bhist,
    unsigned int* __restrict__ ebuf, int* __restrict__ bstart,
    const unsigned short* __restrict__ xh, const unsigned short* __restrict__ xl,
    const unsigned short* __restrict__ wt_in, const float* __restrict__ b_in,
    unsigned short* __restrict__ h0h, unsigned short* __restrict__ h0l) {
    __shared__ unsigned short smem[64 * (256 + 8)];   // 33792 B (proj needs it)
    if (blockIdx.x < NBLK) {
        scatter_body(blockIdx.x, ei, bhist, ebuf, bstart, (int*)smem);
    } else {
        gemm_body<256, 64, 0, 1>(smem, (int)(blockIdx.x - NBLK) * 64,
                                 xh, xl, wt_in, b_in, h0h,
                                 nullptr, nullptr, nullptr, nullptr,
                                 nullptr, nullptr, nullptr, nullptr, nullptr, nullptr,
                                 h0l, nullptr, NN);
    }
}

// K3: build_csr (blocks [0,NBUK)) || layer-0 GEMM+scores (blocks [NBUK, NBUK+GEMM_BLKS))
__global__ __launch_bounds__(256) void build_l0(
    const unsigned int* __restrict__ ebuf, const int* __restrict__ bstart,
    int* __restrict__ off, int* __restrict__ csr,
    const unsigned short* __restrict__ h0h, const unsigned short* __restrict__ h0l,
    const unsigned short* __restrict__ wt_l0,
    unsigned short* __restrict__ hh,
    const float* __restrict__ a_src, const float* __restrict__ a_dst,
    float* __restrict__ ssrc, float* __restrict__ sdst) {
    __shared__ unsigned short smem[64 * (64 + 8)];    // 9216 B (l0 gemm needs it)
    if (blockIdx.x < NBUK) {
        build_body(blockIdx.x, ebuf, bstart, off, csr, (int*)smem);
    } else {
        gemm_body<64, 256, 1, 4>(smem, (int)(blockIdx.x - NBUK) * 64,
                                 h0h, h0l, wt_l0, nullptr, hh,
                                 a_src, a_dst, ssrc, sdst,
                                 nullptr, nullptr, nullptr, nullptr, nullptr, nullptr,
                                 nullptr, nullptr, NN);
    }
}

// standalone GEMM wrapper (layers 1,2 and heads)
template <int K, int OUT_CH, int MODE, int NT>
__global__ __launch_bounds__(256) void gemm_lds(
    const unsigned short* __restrict__ Ahp, const unsigned short* __restrict__ Alp,
    const unsigned short* __restrict__ Wh,
    const float* __restrict__ bias,
    unsigned short* __restrict__ Outh, unsigned short* __restrict__ Outl,
    const float* __restrict__ a_src, const float* __restrict__ a_dst,
    float* __restrict__ s_src, float* __restrict__ s_dst,
    const float* __restrict__ w2n, const float* __restrict__ w2o,
    const float* __restrict__ w2e,
    const float* __restrict__ b2n, const float* __restrict__ b2o,
    const float* __restrict__ b2e,
    float* __restrict__ outbuf, int nreal) {
    __shared__ unsigned short Bh[64 * (K + 8)];
    gemm_body<K, OUT_CH, MODE, NT>(Bh, blockIdx.x * 64, Ahp, Alp, Wh, bias, Outh,
                                   a_src, a_dst, s_src, s_dst,
                                   w2n, w2o, w2e, b2n, b2o, b2e, Outl, outbuf, nreal);
}

// ---------------- per-dst-node GAT aggregation (R1 form, proven 46.8us) ----------------
__global__ __launch_bounds__(256) void gat_node(const unsigned short* __restrict__ hhb,
                                                const float* __restrict__ s_src,
                                                const float* __restrict__ s_dst,
                                                const int* __restrict__ csr_src,
                                                const int* __restrict__ csr_off,
                                                const float* __restrict__ gbias,
                                                const float* __restrict__ conf_w,
                                                const float* __restrict__ conf_b,
                                                const float* __restrict__ confid,
                                                unsigned short* __restrict__ h_hi,
                                                unsigned short* __restrict__ h_lo,
                                                float* __restrict__ outbuf,
                                                int layer) {
    __shared__ float Lc[4][64];
    __shared__ int   Ls[4][16];
    int wv = threadIdx.x >> 6;
    int lane = threadIdx.x & 63;
    int n = blockIdx.x * 4 + wv;
    int myhead = lane >> 4, slot = lane & 15;
    int off0 = csr_off[n];
    int deg = csr_off[n + 1] - off0;     // deg >= 1 (self loop)
    const int* cp = csr_src + off0;
    const unsigned short* hrow = hhb + lane * 4;
    float sdm = s_dst[n * 4 + myhead];

    float ax = 0.f, ay = 0.f, az = 0.f, aw = 0.f, smp = 0.f;
    int nch = (deg + 15) >> 4;
    bool valid = slot < deg;
    int sl = cp[valid ? slot : deg - 1];
    float ssv = s_src[sl * 4 + myhead];
    for (int t = 0; t < nch; t++) {
        float a = ssv + sdm;
        a = a > 0.f ? a : NEG * a;
        float c = valid ? __expf(a) : 0.f;
        smp += c;
        Lc[wv][lane] = c;
        if (myhead == 0) Ls[wv][slot] = sl;
        __builtin_amdgcn_wave_barrier();
        float4 c0 = *(const float4*)&Lc[wv][myhead * 16 + 0];
        float4 c1 = *(const float4*)&Lc[wv][myhead * 16 + 4];
        float4 c2 = *(const float4*)&Lc[wv][myhead * 16 + 8];
        float4 c3 = *(const float4*)&Lc[wv][myhead * 16 + 12];
        int4 s0 = *(const int4*)&Ls[wv][0];
        int4 s1 = *(const int4*)&Ls[wv][4];
        int4 s2 = *(const int4*)&Ls[wv][8];
        int4 s3 = *(const int4*)&Ls[wv][12];
        __builtin_amdgcn_wave_barrier();
        if (t + 1 < nch) {
            int i = ((t + 1) << 4) + slot;
            valid = i < deg;
            sl = cp[valid ? i : deg - 1];
            ssv = s_src[sl * 4 + myhead];
        }
        float cf[16] = {c0.x, c0.y, c0.z, c0.w, c1.x, c1.y, c1.z, c1.w,
                        c2.x, c2.y, c2.z, c2.w, c3.x, c3.y, c3.z, c3.w};
        int sv[16] = {s0.x, s0.y, s0.z, s0.w, s1.x, s1.y, s1.z, s1.w,
                      s2.x, s2.y, s2.z, s2.w, s3.x, s3.y, s3.z, s3.w};
#pragma unroll
        for (int q = 0; q < 16; q++) {
            uint2 u = *(const uint2*)(hrow + ((size_t)sv[q] << 8));
            ax += cf[q] * bf_lo(u.x); ay += cf[q] * bf_hi(u.x);
            az += cf[q] * bf_lo(u.y); aw += cf[q] * bf_hi(u.y);
        }
    }
    smp += __shfl_xor(smp, 1, 64);
    smp += __shfl_xor(smp, 2, 64);
    smp += __shfl_xor(smp, 4, 64);
    smp += __shfl_xor(smp, 8, 64);
    float inv = 1.0f / fmaxf(smp, 1e-16f);
    ax *= inv; ay *= inv; az *= inv; aw *= inv;

    float4 b4 = *(const float4*)&gbias[lane * 4];
    float hx = ax + b4.x, hy = ay + b4.y, hz = az + b4.z, hw = aw + b4.w;
    float4 cw4 = *(const float4*)&conf_w[lane * 4];
    float local = hx * cw4.x + hy * cw4.y + hz * cw4.z + hw * cw4.w;
    float tot = wred_sum(local);
    float cw = sigmoidf_(tot + conf_b[0]) * sigmoidf_(confid[n]);
    hx *= cw; hy *= cw; hz *= cw; hw *= cw;
    if (layer > 0) {
        ushort4 ph = *(const ushort4*)&h_hi[(size_t)n * HC + lane * 4];
        ushort4 pl = *(const ushort4*)&h_lo[(size_t)n * HC + lane * 4];
        hx += bfval(ph.x) + bfval(pl.x);
        hy += bfval(ph.y) + bfval(pl.y);
        hz += bfval(ph.z) + bfval(pl.z);
        hw += bfval(ph.w) + bfval(pl.w);
    }
    if (layer < 2) {
        hx = fmaxf(hx, 0.f); hy = fmaxf(hy, 0.f);
        hz = fmaxf(hz, 0.f); hw = fmaxf(hw, 0.f);
    } else {
        *(float4*)&outbuf[6 * NN + (size_t)n * HC + lane * 4] =
            make_float4(hx, hy, hz, hw);
    }
    ushort4 oh, ol;
    oh.x = f2bf(hx); ol.x = f2bf(hx - bfval(oh.x));
    oh.y = f2bf(hy); ol.y = f2bf(hy - bfval(oh.y));
    oh.z = f2bf(hz); ol.z = f2bf(hz - bfval(oh.z));
    oh.w = f2bf(hw); ol.w = f2bf(hw - bfval(oh.w));
    *(ushort4*)&h_hi[(size_t)n * HC + lane * 4] = oh;
    *(ushort4*)&h_lo[(size_t)n * HC + lane * 4] = ol;
}

extern "C" void kernel_launch(void* const* d_in, const int* in_sizes, int n_in,
                              void* d_out, int out_size, void* d_ws, size_t ws_size,
                              hipStream_t stream) {
    const float* x       = (const float*)d_in[0];
    const int*   ei      = (const int*)d_in[1];
    const float* conf    = (const float*)d_in[2];
    const float* w_in    = (const float*)d_in[3];
    const float* b_in    = (const float*)d_in[4];
    const float* lin_w0  = (const float*)d_in[5];
    const float* lin_w12 = (const float*)d_in[6];
    const float* att_src = (const float*)d_in[7];
    const float* att_dst = (const float*)d_in[8];
    const float* gbias   = (const float*)d_in[9];
    const float* conf_w  = (const float*)d_in[10];
    const float* conf_b  = (const float*)d_in[11];
    const float* nc_w1   = (const float*)d_in[12];
    const float* nc_b1   = (const float*)d_in[13];
    const float* nc_w2   = (const float*)d_in[14];
    const float* nc_b2   = (const float*)d_in[15];
    const float* oc_w1   = (const float*)d_in[16];
    const float* oc_b1   = (const float*)d_in[17];
    const float* oc_w2   = (const float*)d_in[18];
    const float* oc_b2   = (const float*)d_in[19];
    const float* ec_w1   = (const float*)d_in[20];
    const float* ec_b1   = (const float*)d_in[21];
    const float* ec_w2   = (const float*)d_in[22];
    const float* ec_b2   = (const float*)d_in[23];
    float* out = (float*)d_out;

    char* p = (char*)d_ws;
    auto alloc = [&](size_t bytes) -> void* {
        void* r = (void*)p;
        p += (bytes + 255) & ~(size_t)255;
        return r;
    };
    unsigned short* h_hi = (unsigned short*)alloc((size_t)NPAD * HC * 2);
    unsigned short* h_lo = (unsigned short*)alloc((size_t)NPAD * HC * 2);
    unsigned short* hh   = (unsigned short*)alloc((size_t)NPAD * HC * 2);
    unsigned short* h0h  = (unsigned short*)alloc((size_t)NPAD * CC * 2);
    unsigned short* h0l  = (unsigned short*)alloc((size_t)NPAD * CC * 2);
    float*          ssrc = (float*)alloc((size_t)NN * 4 * 4);
    float*          sdst = (float*)alloc((size_t)NN * 4 * 4);
    int*            off  = (int*)alloc((size_t)(NN + 1) * 4);
    int*            csr  = (int*)alloc((size_t)E2 * 4);
    int*            bhist= (int*)alloc((size_t)(NBUK * NBLK) * 4);
    int*            bstart=(int*)alloc((size_t)(NBUK + 1) * 4);
    unsigned int*   ebuf = (unsigned int*)alloc((size_t)E2 * 4);  // own buffer: scatter runs || proj
    unsigned short* whi  = (unsigned short*)alloc((size_t)WTOT * 2);
    float*          bcat = (float*)alloc((size_t)192 * 4);
    unsigned short* xh   = (unsigned short*)alloc((size_t)NPAD * 256 * 2 * 2);
    unsigned short* xl   = xh + (size_t)NPAD * 256;

    const unsigned short* wt_in = whi;
    const unsigned short* wt_l0 = whi + 16384;
    const unsigned short* wt_a  = whi + 32768;
    const unsigned short* wt_b  = whi + 98304;
    const unsigned short* wt_hd = whi + 163840;

    // K1: prep (bf16 split + weight repack) || per-block coarse histogram
    prep_hist<<<PREP_BLKS + NBLK, 256, 0, stream>>>(
        x, w_in, lin_w0, lin_w12, nc_w1, oc_w1, ec_w1, nc_b1, oc_b1, ec_b1,
        whi, bcat, xh, xl, ei, bhist);

    // K2: bucket scatter (wave-parallel self-computed bases) || input proj GEMM
    scatter_proj<<<NBLK + GEMM_BLKS, 256, 0, stream>>>(
        ei, bhist, ebuf, bstart, xh, xl, wt_in, b_in, h0h, h0l);

    // K3: fine CSR build || GAT layer-0 GEMM + attention scores
    build_l0<<<NBUK + GEMM_BLKS, 256, 0, stream>>>(
        ebuf, bstart, off, csr, h0h, h0l, wt_l0, hh, att_src, att_dst, ssrc, sdst);

    gat_node<<<NN / 4, 256, 0, stream>>>(hh, ssrc, sdst, csr, off, gbias, conf_w, conf_b, conf,
                                         h_hi, h_lo, out, 0);

    // GAT layers 1,2 (in=256): 4 col-tiles/block
    for (int i = 1; i < 3; i++) {
        const unsigned short* wh = (i == 1) ? wt_a : wt_b;
        gemm_lds<256, 256, 1, 4><<<dim3(GEMM_BLKS, 1), 256, 0, stream>>>(
            h_hi, h_lo, wh, nullptr, hh, nullptr,
            att_src + i * HHD * CC, att_dst + i * HHD * CC, ssrc, sdst,
            nullptr, nullptr, nullptr, nullptr, nullptr, nullptr, nullptr, NN);
        gat_node<<<NN / 4, 256, 0, stream>>>(hh, ssrc, sdst, csr, off, gbias + i * HC,
                                             conf_w, conf_b, conf, h_hi, h_lo, out, i);
    }

    // fused heads: 3 col-tiles/block (node/origin/etype)
    gemm_lds<256, 192, 3, 3><<<dim3(GEMM_BLKS, 1), 256, 0, stream>>>(
        h_hi, h_lo, wt_hd, bcat, nullptr, nullptr, nullptr, nullptr, nullptr, nullptr,
        nc_w2, oc_w2, ec_w2, nc_b2, oc_b2, ec_b2, out, NN);
}

// Round 16
// 340.377 us; speedup vs baseline: 1.1543x; 1.1543x over previous
//
#include <hip/hip_runtime.h>
#include <cstdint>
#include <cstddef>

#define NN   20000
#define NPAD 20224   // 316*64
#define EE   640000
#define E2   660000   // EE + NN self loops
#define HHD  4
#define CC   64
#define HC   256
#define NEG  0.2f

// counting-sort CSR build geometry
#define NBUK 313     // ceil(20000/64) buckets of 64 dst nodes
#define NBLK 129     // ceil(E2/EPB) edge blocks
#define EPB  5120    // 256 threads * 20 edges
#define PREP_BLKS 5000       // NN*64/256
#define GEMM_BLKS (NPAD / 64) // 316

typedef short bf16x8 __attribute__((ext_vector_type(8)));
typedef float f32x4 __attribute__((ext_vector_type(4)));

__device__ __forceinline__ float sigmoidf_(float x) { return 1.0f / (1.0f + __expf(-x)); }

__device__ __forceinline__ float wred_sum(float v) {
#pragma unroll
    for (int d = 32; d; d >>= 1) v += __shfl_xor(v, d, 64);
    return v;
}

__device__ __forceinline__ unsigned short f2bf(float f) {
    unsigned u = __float_as_uint(f);
    u = (u + 0x7fff + ((u >> 16) & 1)) >> 16;   // RNE
    return (unsigned short)u;
}
__device__ __forceinline__ float bfval(unsigned short h) { return __uint_as_float(((unsigned)h) << 16); }
__device__ __forceinline__ float bf_lo(unsigned u) { return __uint_as_float(u << 16); }
__device__ __forceinline__ float bf_hi(unsigned u) { return __uint_as_float(u & 0xffff0000u); }

// ---------------- device bodies (shared by standalone + fused kernels) ----------------

// hist: BLOCK-MAJOR layout bhist[bl*NBUK + i] -> contiguous (coalesced) store,
// and scatter's per-bucket sums read coalesced columns (fix for R15's 82us:
// bucket-major rows made every sum a stride-516B gather).
__device__ __forceinline__ void hist_body(int bl, const int* __restrict__ ei,
                                          int* __restrict__ bhist, int* h /*LDS NBUK*/) {
    int t = threadIdx.x;
    for (int i = t; i < NBUK; i += 256) h[i] = 0;
    __syncthreads();
    int e0 = bl * EPB;
#pragma unroll 4
    for (int i = t; i < EPB; i += 256) {
        int e = e0 + i;
        if (e < E2) {
            int d = (e < EE) ? ei[EE + e] : (e - EE);
            atomicAdd(&h[d >> 6], 1);
        }
    }
    __syncthreads();
    for (int i = t; i < NBUK; i += 256) bhist[bl * NBUK + i] = h[i];
}

// scatter WITH self-computed bases: derives exactly the old scan values
//   cur[i] = sum_{j<i} total_j + sum_{b<bl} bhist[b][i]
// from the block-major grid: thread i loops over blocks b -> at fixed b,
// consecutive threads read consecutive addresses (coalesced 1KB rounds),
// all loads independent. csr output bit-identical to the scan_hist path.
// Block 0 publishes bucket starts + E2 sentinel for build_body.
__device__ __forceinline__ void scatter_body(int bl, const int* __restrict__ ei,
                                             const int* __restrict__ bhist,
                                             unsigned int* __restrict__ ebuf,
                                             int* __restrict__ bstart,
                                             int* ih /*LDS >= 2*NBUK+256+NBUK ints*/) {
    int* tot = ih;                  // [NBUK]
    int* par = ih + NBUK;           // [NBUK]
    int* buf = ih + 2 * NBUK;       // [256]
    int* cur = ih + 2 * NBUK + 256; // [NBUK]
    int t = threadIdx.x;
    // thread-parallel per-bucket sums; coalesced across threads at each b
    for (int i = t; i < NBUK; i += 256) {
        int st = 0, sp = 0;
        for (int b = 0; b < NBLK; b++) {
            int v = bhist[b * NBUK + i];
            st += v;
            if (b < bl) sp += v;
        }
        tot[i] = st; par[i] = sp;
    }
    __syncthreads();
    // exclusive scan over bucket totals: thread t owns buckets 2t, 2t+1
    int b0 = t * 2;
    int v0 = (b0 < NBUK) ? tot[b0] : 0;
    int v1 = (b0 + 1 < NBUK) ? tot[b0 + 1] : 0;
    int s = v0 + v1;
    buf[t] = s;
    __syncthreads();
    for (int d = 1; d < 256; d <<= 1) {
        int tv = (t >= d) ? buf[t - d] : 0;
        __syncthreads();
        buf[t] += tv;
        __syncthreads();
    }
    int excl = buf[t] - s;
    if (b0 < NBUK)     cur[b0]     = excl + par[b0];
    if (b0 + 1 < NBUK) cur[b0 + 1] = excl + v0 + par[b0 + 1];
    if (bl == 0) {   // publish bucket starts for build_body (par==0 here)
        if (b0 < NBUK)     bstart[b0]     = excl;
        if (b0 + 1 < NBUK) bstart[b0 + 1] = excl + v0;
        if (t == 0) bstart[NBUK] = E2;
    }
    __syncthreads();
    int e0 = bl * EPB;
#pragma unroll 4
    for (int i = t; i < EPB; i += 256) {
        int e = e0 + i;
        if (e < E2) {
            int s2, d;
            if (e < EE) { s2 = ei[e]; d = ei[EE + e]; }
            else        { s2 = e - EE; d = s2; }
            int p = atomicAdd(&cur[d >> 6], 1);
            ebuf[p] = ((unsigned int)(d & 63) << 15) | (unsigned int)s2;
        }
    }
}

__device__ __forceinline__ void build_body(int bu, const unsigned int* __restrict__ ebuf,
                                           const int* __restrict__ bstart,
                                           int* __restrict__ off, int* __restrict__ csr,
                                           int* hist /*LDS 192 ints: hist|sc|curl*/) {
    int* sc = hist + 64;
    int* curl = hist + 128;
    int t = threadIdx.x;
    int base = bstart[bu];
    int end  = bstart[bu + 1];
    int ne = end - base;
    if (t < 64) hist[t] = 0;
    __syncthreads();
    for (int i = t; i < ne; i += 256) {
        int dl = (int)(ebuf[base + i] >> 15);
        atomicAdd(&hist[dl], 1);
    }
    __syncthreads();
    if (t < 64) sc[t] = hist[t];
    __syncthreads();
    for (int d = 1; d < 64; d <<= 1) {
        int v = (t < 64 && t >= d) ? sc[t - d] : 0;
        __syncthreads();
        if (t < 64) sc[t] += v;
        __syncthreads();
    }
    int n0 = bu * 64;
    if (t < 64) {
        int ex = base + sc[t] - hist[t];   // exclusive prefix -> global offset
        if (n0 + t < NN) off[n0 + t] = ex;
        curl[t] = ex;
    }
    if (bu == NBUK - 1 && t == 0) off[NN] = E2;
    __syncthreads();
    for (int i = t; i < ne; i += 256) {
        unsigned int v = ebuf[base + i];
        int dl = (int)(v >> 15);
        int p = atomicAdd(&curl[dl], 1);
        csr[p] = (int)(v & 0x7fffu);
    }
}

#define WTOT 212992
__device__ __forceinline__ void prep_body(int idx,
                            const float* __restrict__ x,
                            const float* __restrict__ w_in, const float* __restrict__ lin_w0,
                            const float* __restrict__ lin_w12,
                            const float* __restrict__ nc1, const float* __restrict__ oc1,
                            const float* __restrict__ ec1,
                            const float* __restrict__ nb, const float* __restrict__ ob,
                            const float* __restrict__ eb,
                            unsigned short* __restrict__ whi,
                            float* __restrict__ bcat,
                            unsigned short* __restrict__ xh, unsigned short* __restrict__ xl) {
    if (idx < NN * 64) {
        float4 v = ((const float4*)x)[idx];
        ushort4 hi, lo;
        hi.x = f2bf(v.x); lo.x = f2bf(v.x - bfval(hi.x));
        hi.y = f2bf(v.y); lo.y = f2bf(v.y - bfval(hi.y));
        hi.z = f2bf(v.z); lo.z = f2bf(v.z - bfval(hi.z));
        hi.w = f2bf(v.w); lo.w = f2bf(v.w - bfval(hi.w));
        ((ushort4*)xh)[idx] = hi;
        ((ushort4*)xl)[idx] = lo;
    }
    if (idx < 192) {
        int g = idx >> 6, jj = idx & 63;
        const float* b = (g == 0) ? nb : ((g == 1) ? ob : eb);
        bcat[idx] = b[jj];
    }
    if (idx >= WTOT) return;
    float v;
    if (idx < 16384) {
        int n = idx >> 8, k = idx & 255;
        v = w_in[k * 64 + n];
    } else if (idx < 32768) {
        int r = idx - 16384;
        int n = r >> 6, k = r & 63;
        v = lin_w0[k * 256 + n];
    } else if (idx < 98304) {
        int r = idx - 32768;
        int n = r >> 8, k = r & 255;
        v = lin_w12[k * 256 + n];
    } else if (idx < 163840) {
        int r = idx - 98304;
        int n = r >> 8, k = r & 255;
        v = lin_w12[65536 + k * 256 + n];
    } else {
        int r = idx - 163840;
        int n = r >> 8, k = r & 255;
        int g = n >> 6, jj = n & 63;
        const float* w = (g == 0) ? nc1 : ((g == 1) ? oc1 : ec1);
        v = w[k * 64 + jj];
    }
    whi[idx] = f2bf(v);
}

// ---------------- 2-term split MFMA GEMM body: full-K A prefetch + LDS B ----------------
// NT col-tiles processed SEQUENTIALLY: A fragments loaded once, resident across tiles.
// MODE 0: bias+relu -> hi/lo planes.
// MODE 1: bf16 out (gat gather plane) + fused ATTN scores (ct == head).
// MODE 3: fused output heads (ct: 0=node,1=origin,2=etype).
template <int K, int OUT_CH, int MODE, int NT>
__device__ __forceinline__ void gemm_body(
    unsigned short* Bh,   // LDS: 64*(K+8) shorts
    int mb,
    const unsigned short* __restrict__ Ahp, const unsigned short* __restrict__ Alp,
    const unsigned short* __restrict__ Wh,
    const float* __restrict__ bias,
    unsigned short* __restrict__ Outh,
    const float* __restrict__ a_src, const float* __restrict__ a_dst,
    float* __restrict__ s_src, float* __restrict__ s_dst,
    const float* __restrict__ w2n, const float* __restrict__ w2o,
    const float* __restrict__ w2e,
    const float* __restrict__ b2n, const float* __restrict__ b2o,
    const float* __restrict__ b2e,
    unsigned short* __restrict__ Outl,
    float* __restrict__ outbuf, int nreal) {
    constexpr int LB = K + 8;                 // shorts per padded LDS row
    constexpr int NS = K / 32;                // k-steps
    const int tid = threadIdx.x;
    const int wv = tid >> 6, lane = tid & 63;
    const int quad = lane >> 4, ln = lane & 15;
    const int r0 = mb + wv * 16 + ln;

    // 1) issue ALL A-fragment loads once (kept resident across the NT tiles)
    const unsigned short* aph = Ahp + (size_t)r0 * K + quad * 8;
    const unsigned short* apl = Alp + (size_t)r0 * K + quad * 8;
    bf16x8 ah[NS], al[NS];
#pragma unroll
    for (int s = 0; s < NS; s++) {
        ah[s] = *(const bf16x8*)(aph + s * 32);
        al[s] = *(const bf16x8*)(apl + s * 32);
    }

    for (int ct = 0; ct < NT; ct++) {
        const int cb = ct * 64;
        if (ct > 0) __syncthreads();          // previous B tile fully consumed

        // 2) stage B tile into LDS (rows cb..cb+63, k-contig, padded rows)
        constexpr int NCHK = 64 * (K / 8);
#pragma unroll
        for (int i = 0; i < NCHK / 256; i++) {
            int flat = tid + i * 256;
            int r = flat / (K / 8);
            int c = (flat % (K / 8)) * 8;
            *(uint4*)&Bh[r * LB + c] = *(const uint4*)&Wh[(size_t)(cb + r) * K + c];
        }
        __syncthreads();

        f32x4 acc[4];
#pragma unroll
        for (int j = 0; j < 4; j++) {
            acc[j][0] = 0.f; acc[j][1] = 0.f; acc[j][2] = 0.f; acc[j][3] = 0.f;
        }

        // 3) K-loop: LDS B reads + MFMA only (2-term: ah*bh + al*bh)
#pragma unroll
        for (int s = 0; s < NS; s++) {
#pragma unroll
            for (int cg = 0; cg < 4; cg++) {
                bf16x8 bh = *(const bf16x8*)&Bh[(cg * 16 + ln) * LB + quad * 8 + s * 32];
                acc[cg] = __builtin_amdgcn_mfma_f32_16x16x32_bf16(ah[s], bh, acc[cg], 0, 0, 0);
                acc[cg] = __builtin_amdgcn_mfma_f32_16x16x32_bf16(al[s], bh, acc[cg], 0, 0, 0);
            }
        }

        if (MODE == 1) {
            // per-tile == per-head: score over this head's 64 cols only
            float av[4], dv[4];
#pragma unroll
            for (int cg = 0; cg < 4; cg++) {
                av[cg] = a_src[cb + cg * 16 + ln];
                dv[cg] = a_dst[cb + cg * 16 + ln];
            }
#pragma unroll
            for (int reg = 0; reg < 4; reg++) {
                float ps = 0.f, pd = 0.f;
#pragma unroll
                for (int cg = 0; cg < 4; cg++) {
                    float t = acc[cg][reg];
                    ps += t * av[cg];
                    pd += t * dv[cg];
                }
#pragma unroll
                for (int d = 1; d < 16; d <<= 1) {
                    ps += __shfl_xor(ps, d, 64);
                    pd += __shfl_xor(pd, d, 64);
                }
                if (ln == 0) {
                    int row = mb + wv * 16 + quad * 4 + reg;
                    if (row < nreal) {
                        s_src[row * 4 + ct] = ps;
                        s_dst[row * 4 + ct] = pd;
                    }
                }
            }
        }

        if (MODE == 3) {
            float bv[4];
#pragma unroll
            for (int cg = 0; cg < 4; cg++) bv[cg] = bias[cb + cg * 16 + ln];
            if (ct < 2) {
                const float* w2 = (ct == 0) ? w2n : w2o;
                float b2 = (ct == 0) ? b2n[0] : b2o[0];
                float wv2[4];
#pragma unroll
                for (int cg = 0; cg < 4; cg++) wv2[cg] = w2[cg * 16 + ln];
#pragma unroll
                for (int reg = 0; reg < 4; reg++) {
                    float t = 0.f;
#pragma unroll
                    for (int cg = 0; cg < 4; cg++) {
                        float tv = fmaxf(acc[cg][reg] + bv[cg], 0.f);
                        t += tv * wv2[cg];
                    }
#pragma unroll
                    for (int d = 1; d < 16; d <<= 1) t += __shfl_xor(t, d, 64);
                    int row = mb + wv * 16 + quad * 4 + reg;
                    if (ln == 0 && row < nreal)
                        outbuf[ct * NN + row] = sigmoidf_(t + b2);
                }
            } else {
                float4 w4[4];
#pragma unroll
                for (int cg = 0; cg < 4; cg++) w4[cg] = ((const float4*)w2e)[cg * 16 + ln];
#pragma unroll
                for (int reg = 0; reg < 4; reg++) {
                    float e0 = 0.f, e1 = 0.f, e2 = 0.f, e3 = 0.f;
#pragma unroll
                    for (int cg = 0; cg < 4; cg++) {
                        float tv = fmaxf(acc[cg][reg] + bv[cg], 0.f);
                        e0 += tv * w4[cg].x; e1 += tv * w4[cg].y;
                        e2 += tv * w4[cg].z; e3 += tv * w4[cg].w;
                    }
#pragma unroll
                    for (int d = 1; d < 16; d <<= 1) {
                        e0 += __shfl_xor(e0, d, 64); e1 += __shfl_xor(e1, d, 64);
                        e2 += __shfl_xor(e2, d, 64); e3 += __shfl_xor(e3, d, 64);
                    }
                    int row = mb + wv * 16 + quad * 4 + reg;
                    if (ln == 0 && row < nreal) {
                        float4 ev = make_float4(e0 + b2e[0], e1 + b2e[1], e2 + b2e[2], e3 + b2e[3]);
                        *(float4*)&outbuf[2 * NN + row * 4] = ev;
                    }
                }
            }
            continue;
        }

        // D layout: row = quad*4 + reg, col = ln (within each 16x16 tile)
#pragma unroll
        for (int cg = 0; cg < 4; cg++) {
            int col = cb + cg * 16 + ln;
            int rbase = mb + wv * 16 + quad * 4;
#pragma unroll
            for (int reg = 0; reg < 4; reg++) {
                float v = acc[cg][reg];
                int r = rbase + reg;
                if (MODE == 0) {
                    v += bias[col]; v = fmaxf(v, 0.f);
                    unsigned short hi = f2bf(v);
                    Outh[(size_t)r * OUT_CH + col] = hi;
                    Outl[(size_t)r * OUT_CH + col] = f2bf(v - bfval(hi));
                } else if (MODE == 1) {
                    Outh[(size_t)r * OUT_CH + col] = f2bf(v);
                }
            }
        }
    }
}

// ---------------- fused + standalone kernels ----------------

// K1: prep (blocks [0,PREP_BLKS)) || hist (blocks [PREP_BLKS, PREP_BLKS+NBLK))
__global__ __launch_bounds__(256) void prep_hist(
    const float* __restrict__ x,
    const float* __restrict__ w_in, const float* __restrict__ lin_w0,
    const float* __restrict__ lin_w12,
    const float* __restrict__ nc1, const float* __restrict__ oc1,
    const float* __restrict__ ec1,
    const float* __restrict__ nb, const float* __restrict__ ob,
    const float* __restrict__ eb,
    unsigned short* __restrict__ whi, float* __restrict__ bcat,
    unsigned short* __restrict__ xh, unsigned short* __restrict__ xl,
    const int* __restrict__ ei, int* __restrict__ bhist) {
    __shared__ int h[NBUK];
    if (blockIdx.x < PREP_BLKS) {
        prep_body(blockIdx.x * 256 + threadIdx.x, x, w_in, lin_w0, lin_w12,
                  nc1, oc1, ec1, nb, ob, eb, whi, bcat, xh, xl);
    } else {
        hist_body(blockIdx.x - PREP_BLKS, ei, bhist, h);
    }
}

// K2: scatter w/ self-computed bases (blocks [0,NBLK)) || input-proj GEMM
__global__ __launch_bounds__(256) void scatter_proj(
    const int* __restrict__ ei, const int* __restrict__ bhist,
    unsigned int* __restrict__ ebuf, int* __restrict__ bstart,
    const unsigned short* __restrict__ xh, const unsigned short* __restrict__ xl,
    const unsigned short* __restrict__ wt_in, const float* __restrict__ b_in,
    unsigned short* __restrict__ h0h, unsigned short* __restrict__ h0l) {
    __shared__ unsigned short smem[64 * (256 + 8)];   // 33792 B (proj needs it)
    if (blockIdx.x < NBLK) {
        scatter_body(blockIdx.x, ei, bhist, ebuf, bstart, (int*)smem);
    } else {
        gemm_body<256, 64, 0, 1>(smem, (int)(blockIdx.x - NBLK) * 64,
                                 xh, xl, wt_in, b_in, h0h,
                                 nullptr, nullptr, nullptr, nullptr,
                                 nullptr, nullptr, nullptr, nullptr, nullptr, nullptr,
                                 h0l, nullptr, NN);
    }
}

// K3: build_csr (blocks [0,NBUK)) || layer-0 GEMM+scores (blocks [NBUK, NBUK+GEMM_BLKS))
__global__ __launch_bounds__(256) void build_l0(
    const unsigned int* __restrict__ ebuf, const int* __restrict__ bstart,
    int* __restrict__ off, int* __restrict__ csr,
    const unsigned short* __restrict__ h0h, const unsigned short* __restrict__ h0l,
    const unsigned short* __restrict__ wt_l0,
    unsigned short* __restrict__ hh,
    const float* __restrict__ a_src, const float* __restrict__ a_dst,
    float* __restrict__ ssrc, float* __restrict__ sdst) {
    __shared__ unsigned short smem[64 * (64 + 8)];    // 9216 B (l0 gemm needs it)
    if (blockIdx.x < NBUK) {
        build_body(blockIdx.x, ebuf, bstart, off, csr, (int*)smem);
    } else {
        gemm_body<64, 256, 1, 4>(smem, (int)(blockIdx.x - NBUK) * 64,
                                 h0h, h0l, wt_l0, nullptr, hh,
                                 a_src, a_dst, ssrc, sdst,
                                 nullptr, nullptr, nullptr, nullptr, nullptr, nullptr,
                                 nullptr, nullptr, NN);
    }
}

// standalone GEMM wrapper (layers 1,2 and heads)
template <int K, int OUT_CH, int MODE, int NT>
__global__ __launch_bounds__(256) void gemm_lds(
    const unsigned short* __restrict__ Ahp, const unsigned short* __restrict__ Alp,
    const unsigned short* __restrict__ Wh,
    const float* __restrict__ bias,
    unsigned short* __restrict__ Outh, unsigned short* __restrict__ Outl,
    const float* __restrict__ a_src, const float* __restrict__ a_dst,
    float* __restrict__ s_src, float* __restrict__ s_dst,
    const float* __restrict__ w2n, const float* __restrict__ w2o,
    const float* __restrict__ w2e,
    const float* __restrict__ b2n, const float* __restrict__ b2o,
    const float* __restrict__ b2e,
    float* __restrict__ outbuf, int nreal) {
    __shared__ unsigned short Bh[64 * (K + 8)];
    gemm_body<K, OUT_CH, MODE, NT>(Bh, blockIdx.x * 64, Ahp, Alp, Wh, bias, Outh,
                                   a_src, a_dst, s_src, s_dst,
                                   w2n, w2o, w2e, b2n, b2o, b2e, Outl, outbuf, nreal);
}

// ---------------- per-dst-node GAT aggregation (R1 form, proven 46.8us) ----------------
__global__ __launch_bounds__(256) void gat_node(const unsigned short* __restrict__ hhb,
                                                const float* __restrict__ s_src,
                                                const float* __restrict__ s_dst,
                                                const int* __restrict__ csr_src,
                                                const int* __restrict__ csr_off,
                                                const float* __restrict__ gbias,
                                                const float* __restrict__ conf_w,
                                                const float* __restrict__ conf_b,
                                                const float* __restrict__ confid,
                                                unsigned short* __restrict__ h_hi,
                                                unsigned short* __restrict__ h_lo,
                                                float* __restrict__ outbuf,
                                                int layer) {
    __shared__ float Lc[4][64];
    __shared__ int   Ls[4][16];
    int wv = threadIdx.x >> 6;
    int lane = threadIdx.x & 63;
    int n = blockIdx.x * 4 + wv;
    int myhead = lane >> 4, slot = lane & 15;
    int off0 = csr_off[n];
    int deg = csr_off[n + 1] - off0;     // deg >= 1 (self loop)
    const int* cp = csr_src + off0;
    const unsigned short* hrow = hhb + lane * 4;
    float sdm = s_dst[n * 4 + myhead];

    float ax = 0.f, ay = 0.f, az = 0.f, aw = 0.f, smp = 0.f;
    int nch = (deg + 15) >> 4;
    bool valid = slot < deg;
    int sl = cp[valid ? slot : deg - 1];
    float ssv = s_src[sl * 4 + myhead];
    for (int t = 0; t < nch; t++) {
        float a = ssv + sdm;
        a = a > 0.f ? a : NEG * a;
        float c = valid ? __expf(a) : 0.f;
        smp += c;
        Lc[wv][lane] = c;
        if (myhead == 0) Ls[wv][slot] = sl;
        __builtin_amdgcn_wave_barrier();
        float4 c0 = *(const float4*)&Lc[wv][myhead * 16 + 0];
        float4 c1 = *(const float4*)&Lc[wv][myhead * 16 + 4];
        float4 c2 = *(const float4*)&Lc[wv][myhead * 16 + 8];
        float4 c3 = *(const float4*)&Lc[wv][myhead * 16 + 12];
        int4 s0 = *(const int4*)&Ls[wv][0];
        int4 s1 = *(const int4*)&Ls[wv][4];
        int4 s2 = *(const int4*)&Ls[wv][8];
        int4 s3 = *(const int4*)&Ls[wv][12];
        __builtin_amdgcn_wave_barrier();
        if (t + 1 < nch) {
            int i = ((t + 1) << 4) + slot;
            valid = i < deg;
            sl = cp[valid ? i : deg - 1];
            ssv = s_src[sl * 4 + myhead];
        }
        float cf[16] = {c0.x, c0.y, c0.z, c0.w, c1.x, c1.y, c1.z, c1.w,
                        c2.x, c2.y, c2.z, c2.w, c3.x, c3.y, c3.z, c3.w};
        int sv[16] = {s0.x, s0.y, s0.z, s0.w, s1.x, s1.y, s1.z, s1.w,
                      s2.x, s2.y, s2.z, s2.w, s3.x, s3.y, s3.z, s3.w};
#pragma unroll
        for (int q = 0; q < 16; q++) {
            uint2 u = *(const uint2*)(hrow + ((size_t)sv[q] << 8));
            ax += cf[q] * bf_lo(u.x); ay += cf[q] * bf_hi(u.x);
            az += cf[q] * bf_lo(u.y); aw += cf[q] * bf_hi(u.y);
        }
    }
    smp += __shfl_xor(smp, 1, 64);
    smp += __shfl_xor(smp, 2, 64);
    smp += __shfl_xor(smp, 4, 64);
    smp += __shfl_xor(smp, 8, 64);
    float inv = 1.0f / fmaxf(smp, 1e-16f);
    ax *= inv; ay *= inv; az *= inv; aw *= inv;

    float4 b4 = *(const float4*)&gbias[lane * 4];
    float hx = ax + b4.x, hy = ay + b4.y, hz = az + b4.z, hw = aw + b4.w;
    float4 cw4 = *(const float4*)&conf_w[lane * 4];
    float local = hx * cw4.x + hy * cw4.y + hz * cw4.z + hw * cw4.w;
    float tot = wred_sum(local);
    float cw = sigmoidf_(tot + conf_b[0]) * sigmoidf_(confid[n]);
    hx *= cw; hy *= cw; hz *= cw; hw *= cw;
    if (layer > 0) {
        ushort4 ph = *(const ushort4*)&h_hi[(size_t)n * HC + lane * 4];
        ushort4 pl = *(const ushort4*)&h_lo[(size_t)n * HC + lane * 4];
        hx += bfval(ph.x) + bfval(pl.x);
        hy += bfval(ph.y) + bfval(pl.y);
        hz += bfval(ph.z) + bfval(pl.z);
        hw += bfval(ph.w) + bfval(pl.w);
    }
    if (layer < 2) {
        hx = fmaxf(hx, 0.f); hy = fmaxf(hy, 0.f);
        hz = fmaxf(hz, 0.f); hw = fmaxf(hw, 0.f);
    } else {
        *(float4*)&outbuf[6 * NN + (size_t)n * HC + lane * 4] =
            make_float4(hx, hy, hz, hw);
    }
    ushort4 oh, ol;
    oh.x = f2bf(hx); ol.x = f2bf(hx - bfval(oh.x));
    oh.y = f2bf(hy); ol.y = f2bf(hy - bfval(oh.y));
    oh.z = f2bf(hz); ol.z = f2bf(hz - bfval(oh.z));
    oh.w = f2bf(hw); ol.w = f2bf(hw - bfval(oh.w));
    *(ushort4*)&h_hi[(size_t)n * HC + lane * 4] = oh;
    *(ushort4*)&h_lo[(size_t)n * HC + lane * 4] = ol;
}

extern "C" void kernel_launch(void* const* d_in, const int* in_sizes, int n_in,
                              void* d_out, int out_size, void* d_ws, size_t ws_size,
                              hipStream_t stream) {
    const float* x       = (const float*)d_in[0];
    const int*   ei      = (const int*)d_in[1];
    const float* conf    = (const float*)d_in[2];
    const float* w_in    = (const float*)d_in[3];
    const float* b_in    = (const float*)d_in[4];
    const float* lin_w0  = (const float*)d_in[5];
    const float* lin_w12 = (const float*)d_in[6];
    const float* att_src = (const float*)d_in[7];
    const float* att_dst = (const float*)d_in[8];
    const float* gbias   = (const float*)d_in[9];
    const float* conf_w  = (const float*)d_in[10];
    const float* conf_b  = (const float*)d_in[11];
    const float* nc_w1   = (const float*)d_in[12];
    const float* nc_b1   = (const float*)d_in[13];
    const float* nc_w2   = (const float*)d_in[14];
    const float* nc_b2   = (const float*)d_in[15];
    const float* oc_w1   = (const float*)d_in[16];
    const float* oc_b1   = (const float*)d_in[17];
    const float* oc_w2   = (const float*)d_in[18];
    const float* oc_b2   = (const float*)d_in[19];
    const float* ec_w1   = (const float*)d_in[20];
    const float* ec_b1   = (const float*)d_in[21];
    const float* ec_w2   = (const float*)d_in[22];
    const float* ec_b2   = (const float*)d_in[23];
    float* out = (float*)d_out;

    char* p = (char*)d_ws;
    auto alloc = [&](size_t bytes) -> void* {
        void* r = (void*)p;
        p += (bytes + 255) & ~(size_t)255;
        return r;
    };
    unsigned short* h_hi = (unsigned short*)alloc((size_t)NPAD * HC * 2);
    unsigned short* h_lo = (unsigned short*)alloc((size_t)NPAD * HC * 2);
    unsigned short* hh   = (unsigned short*)alloc((size_t)NPAD * HC * 2);
    unsigned short* h0h  = (unsigned short*)alloc((size_t)NPAD * CC * 2);
    unsigned short* h0l  = (unsigned short*)alloc((size_t)NPAD * CC * 2);
    float*          ssrc = (float*)alloc((size_t)NN * 4 * 4);
    float*          sdst = (float*)alloc((size_t)NN * 4 * 4);
    int*            off  = (int*)alloc((size_t)(NN + 1) * 4);
    int*            csr  = (int*)alloc((size_t)E2 * 4);
    int*            bhist= (int*)alloc((size_t)(NBUK * NBLK) * 4);
    int*            bstart=(int*)alloc((size_t)(NBUK + 1) * 4);
    unsigned int*   ebuf = (unsigned int*)alloc((size_t)E2 * 4);  // own buffer: scatter runs || proj
    unsigned short* whi  = (unsigned short*)alloc((size_t)WTOT * 2);
    float*          bcat = (float*)alloc((size_t)192 * 4);
    unsigned short* xh   = (unsigned short*)alloc((size_t)NPAD * 256 * 2 * 2);
    unsigned short* xl   = xh + (size_t)NPAD * 256;

    const unsigned short* wt_in = whi;
    const unsigned short* wt_l0 = whi + 16384;
    const unsigned short* wt_a  = whi + 32768;
    const unsigned short* wt_b  = whi + 98304;
    const unsigned short* wt_hd = whi + 163840;

    // K1: prep (bf16 split + weight repack) || per-block coarse histogram
    prep_hist<<<PREP_BLKS + NBLK, 256, 0, stream>>>(
        x, w_in, lin_w0, lin_w12, nc_w1, oc_w1, ec_w1, nc_b1, oc_b1, ec_b1,
        whi, bcat, xh, xl, ei, bhist);

    // K2: bucket scatter (coalesced self-computed bases) || input proj GEMM
    scatter_proj<<<NBLK + GEMM_BLKS, 256, 0, stream>>>(
        ei, bhist, ebuf, bstart, xh, xl, wt_in, b_in, h0h, h0l);

    // K3: fine CSR build || GAT layer-0 GEMM + attention scores
    build_l0<<<NBUK + GEMM_BLKS, 256, 0, stream>>>(
        ebuf, bstart, off, csr, h0h, h0l, wt_l0, hh, att_src, att_dst, ssrc, sdst);

    gat_node<<<NN / 4, 256, 0, stream>>>(hh, ssrc, sdst, csr, off, gbias, conf_w, conf_b, conf,
                                         h_hi, h_lo, out, 0);

    // GAT layers 1,2 (in=256): 4 col-tiles/block
    for (int i = 1; i < 3; i++) {
        const unsigned short* wh = (i == 1) ? wt_a : wt_b;
        gemm_lds<256, 256, 1, 4><<<dim3(GEMM_BLKS, 1), 256, 0, stream>>>(
            h_hi, h_lo, wh, nullptr, hh, nullptr,
            att_src + i * HHD * CC, att_dst + i * HHD * CC, ssrc, sdst,
            nullptr, nullptr, nullptr, nullptr, nullptr, nullptr, nullptr, NN);
        gat_node<<<NN / 4, 256, 0, stream>>>(hh, ssrc, sdst, csr, off, gbias + i * HC,
                                             conf_w, conf_b, conf, h_hi, h_lo, out, i);
    }

    // fused heads: 3 col-tiles/block (node/origin/etype)
    gemm_lds<256, 192, 3, 3><<<dim3(GEMM_BLKS, 1), 256, 0, stream>>>(
        h_hi, h_lo, wt_hd, bcat, nullptr, nullptr, nullptr, nullptr, nullptr, nullptr,
        nc_w2, oc_w2, ec_w2, nc_b2, oc_b2, ec_b2, out, NN);
}